// Round 6
// baseline (506.950 us; speedup 1.0000x reference)
//
#include <hip/hip_runtime.h>

// ViterbiLoss (CRF forward) on MI355X — v6b: single-wave chains, zero-sync hot loop.
// Meet-in-the-middle split (unchanged math): for batch b, last=len-1, m=last/2:
//   forward  chain: s_t[j] = lse_i(M_t[i,j] + s_{t-1}[i]),  t = 1..m
//   backward chain: g_t[i] = lse_j(M_{t+1}[i,j] + g_{t+1}[j]), t = last-2..m,
//                   init g_{last-1}[i] = M_last[i,STOP]
//   result_b = lse_k(s_m[k] + g_m[k]);  total = sum_b result_b - gold.
// Structure: ONE WAVE per chain (256 blocks x 64 threads). Lane j owns state j.
// Cross-lane broadcast of s[i] via v_readlane (constant index -> SGPR operand):
// NO LDS, NO barriers, NO inline asm in the hot loop. Scores in log2 domain
// pinned to lane 0 (s2[0]==0 invariant -> no overflow, no max reduce);
// natural-log offset accumulated in c. exp(M+s) = v_fma(M,log2e,s2_i)+v_exp_f32.
// Features in a 3-deep named-register ring (144 VGPR), compiler-counted vmcnt.
// v6b de-risk vs v6: std exp2f/__log2f instead of amdgcn builtins (compile
// certainty); backward loads as 12x float4 per step (row is 192B-aligned)
// instead of 48 scalar gathers. Forward stays scalar column loads (each inst
// covers 48 consecutive floats across lanes = coalesced 192B).

#define NB 128
#define NT 256
#define NK 48
#define NKK (NK * NK)          // 2304
#define TAG_START 46
#define TAG_STOP 47
#define K_LOG2E 1.4426950408889634f
#define K_LN2   0.6931471805599453f

#define DECL48(v) \
  float v##0,v##1,v##2,v##3,v##4,v##5,v##6,v##7,v##8,v##9,v##10,v##11, \
        v##12,v##13,v##14,v##15,v##16,v##17,v##18,v##19,v##20,v##21,v##22,v##23, \
        v##24,v##25,v##26,v##27,v##28,v##29,v##30,v##31,v##32,v##33,v##34,v##35, \
        v##36,v##37,v##38,v##39,v##40,v##41,v##42,v##43,v##44,v##45,v##46,v##47;

// forward: lane j owns column j; element i at p[i*NK] (coalesced across lanes)
#define LD48C(v, p) \
  v##0 =(p)[0*NK];  v##1 =(p)[1*NK];  v##2 =(p)[2*NK];  v##3 =(p)[3*NK]; \
  v##4 =(p)[4*NK];  v##5 =(p)[5*NK];  v##6 =(p)[6*NK];  v##7 =(p)[7*NK]; \
  v##8 =(p)[8*NK];  v##9 =(p)[9*NK];  v##10=(p)[10*NK]; v##11=(p)[11*NK]; \
  v##12=(p)[12*NK]; v##13=(p)[13*NK]; v##14=(p)[14*NK]; v##15=(p)[15*NK]; \
  v##16=(p)[16*NK]; v##17=(p)[17*NK]; v##18=(p)[18*NK]; v##19=(p)[19*NK]; \
  v##20=(p)[20*NK]; v##21=(p)[21*NK]; v##22=(p)[22*NK]; v##23=(p)[23*NK]; \
  v##24=(p)[24*NK]; v##25=(p)[25*NK]; v##26=(p)[26*NK]; v##27=(p)[27*NK]; \
  v##28=(p)[28*NK]; v##29=(p)[29*NK]; v##30=(p)[30*NK]; v##31=(p)[31*NK]; \
  v##32=(p)[32*NK]; v##33=(p)[33*NK]; v##34=(p)[34*NK]; v##35=(p)[35*NK]; \
  v##36=(p)[36*NK]; v##37=(p)[37*NK]; v##38=(p)[38*NK]; v##39=(p)[39*NK]; \
  v##40=(p)[40*NK]; v##41=(p)[41*NK]; v##42=(p)[42*NK]; v##43=(p)[43*NK]; \
  v##44=(p)[44*NK]; v##45=(p)[45*NK]; v##46=(p)[46*NK]; v##47=(p)[47*NK];

// backward: lane i owns row i; 48 contiguous floats, 192B-aligned -> 12x float4
#define LD48R(v, p) { \
  const float4* q_ = (const float4*)(p); \
  float4 r0_=q_[0], r1_=q_[1], r2_ =q_[2],  r3_ =q_[3]; \
  float4 r4_=q_[4], r5_=q_[5], r6_ =q_[6],  r7_ =q_[7]; \
  float4 r8_=q_[8], r9_=q_[9], r10_=q_[10], r11_=q_[11]; \
  v##0 =r0_.x;  v##1 =r0_.y;  v##2 =r0_.z;  v##3 =r0_.w; \
  v##4 =r1_.x;  v##5 =r1_.y;  v##6 =r1_.z;  v##7 =r1_.w; \
  v##8 =r2_.x;  v##9 =r2_.y;  v##10=r2_.z;  v##11=r2_.w; \
  v##12=r3_.x;  v##13=r3_.y;  v##14=r3_.z;  v##15=r3_.w; \
  v##16=r4_.x;  v##17=r4_.y;  v##18=r4_.z;  v##19=r4_.w; \
  v##20=r5_.x;  v##21=r5_.y;  v##22=r5_.z;  v##23=r5_.w; \
  v##24=r6_.x;  v##25=r6_.y;  v##26=r6_.z;  v##27=r6_.w; \
  v##28=r7_.x;  v##29=r7_.y;  v##30=r7_.z;  v##31=r7_.w; \
  v##32=r8_.x;  v##33=r8_.y;  v##34=r8_.z;  v##35=r8_.w; \
  v##36=r9_.x;  v##37=r9_.y;  v##38=r9_.z;  v##39=r9_.w; \
  v##40=r10_.x; v##41=r10_.y; v##42=r10_.z; v##43=r10_.w; \
  v##44=r11_.x; v##45=r11_.y; v##46=r11_.z; v##47=r11_.w; }

// broadcast of lane i's s2 (uniform across wave -> SGPR), constant lane index
#define RL(i) __int_as_float(__builtin_amdgcn_readlane(__float_as_int(s2), (i)))
// one LSE term: exp2(M*log2e + s2_i) = e^{M + s_i}
#define TT(v,i) exp2f(__builtin_fmaf(v##i, K_LOG2E, RL(i)))

#define SUMTREE48(v) \
 ((((((TT(v,0)+TT(v,1))+(TT(v,2)+TT(v,3)))+((TT(v,4)+TT(v,5))+(TT(v,6)+TT(v,7)))) + \
    (((TT(v,8)+TT(v,9))+(TT(v,10)+TT(v,11)))+((TT(v,12)+TT(v,13))+(TT(v,14)+TT(v,15))))) + \
   ((((TT(v,16)+TT(v,17))+(TT(v,18)+TT(v,19)))+((TT(v,20)+TT(v,21))+(TT(v,22)+TT(v,23)))) + \
    (((TT(v,24)+TT(v,25))+(TT(v,26)+TT(v,27)))+((TT(v,28)+TT(v,29))+(TT(v,30)+TT(v,31)))))) + \
  ((((TT(v,32)+TT(v,33))+(TT(v,34)+TT(v,35)))+((TT(v,36)+TT(v,37))+(TT(v,38)+TT(v,39)))) + \
   (((TT(v,40)+TT(v,41))+(TT(v,42)+TT(v,43)))+((TT(v,44)+TT(v,45))+(TT(v,46)+TT(v,47))))))

#define STEP48(v, LDM) { \
  float acc_ = SUMTREE48(v); \
  { int up_ = u + 3; if (up_ > nsteps) up_ = nsteps; \
    const float* p_ = basep + (long)up_ * dstep; LDM(v, p_) } \
  float l2_ = __log2f(acc_); \
  float d2_ = __int_as_float(__builtin_amdgcn_readfirstlane(__float_as_int(l2_))); \
  s2 = l2_ - d2_; \
  c  = __builtin_fmaf(d2_, K_LN2, c); \
}

#define CHAIN48(LDM) { \
  DECL48(A) DECL48(B) DECL48(C) \
  { const float* p_ = basep + dstep; LDM(A, p_) } \
  { int up_ = (2 > nsteps) ? nsteps : 2; \
    const float* p_ = basep + (long)up_ * dstep; LDM(B, p_) } \
  { int up_ = (3 > nsteps) ? nsteps : 3; \
    const float* p_ = basep + (long)up_ * dstep; LDM(C, p_) } \
  int u = 1; \
  for (;;) { \
    STEP48(A, LDM) if (++u > nsteps) break; \
    STEP48(B, LDM) if (++u > nsteps) break; \
    STEP48(C, LDM) if (++u > nsteps) break; \
  } \
}

__global__ __launch_bounds__(64, 1)
void viterbi_chain_kernel(const float* __restrict__ feats,
                          const int* __restrict__ targets,
                          const int* __restrict__ lengths,
                          float* __restrict__ out,
                          float* __restrict__ ws)
{
    const int bu   = blockIdx.x;
    const int b    = bu >> 1;
    const int dir  = bu & 1;
    const int lane = threadIdx.x;
    const int len = lengths[b], last = len - 1, m = last >> 1;
    const float* __restrict__ fb = feats + (size_t)b * (NT * NKK);

    // ---- gold slice: fwd owns t in [0,m], bwd owns t in [m+1,last] ----
    float gold = 0.f;
    {
        int t   = dir ? (m + 1 + lane) : lane;
        int tmx = dir ? last : m;
        while (t <= tmx) { gold += fb[(size_t)t * NKK + targets[b * NT + t]]; t += 64; }
        #pragma unroll
        for (int o = 32; o; o >>= 1) gold += __shfl_down(gold, o, 64);
    }

    const int ooc = (lane < NK) ? lane : (NK - 1);   // lanes 48..63 duplicate state 47
    int nsteps = dir ? (last - 1 - m) : m;
    if (nsteps < 0) nsteps = 0;

    // ---- init state (log2 domain): s2 = s_natural * log2e ----
    float s2, c = 0.f;
    if (dir) s2 = (last == 0) ? ((ooc == TAG_STOP) ? 0.f : -1e30f)
                              : fb[(size_t)last * NKK + (size_t)ooc * NK + TAG_STOP] * K_LOG2E;
    else     s2 = fb[TAG_START * NK + ooc] * K_LOG2E;

    if (nsteps > 0) {
        if (dir) {  // backward: lane i reads row i (contiguous 192B, float4 x12)
            const float* basep = fb + (size_t)last * NKK + (size_t)ooc * NK;
            const long dstep = -(long)NKK;
            CHAIN48(LD48R)
        } else {    // forward: lane j reads column j; each load inst is a
                    // contiguous 192B row across lanes (coalesced)
            const float* basep = fb + ooc;
            const long dstep = (long)NKK;
            CHAIN48(LD48C)
        }
    }

    // ---- emit: 48 natural-log values + natural-log offset at [48] ----
    if (lane < NK) ws[(size_t)bu * 64 + lane] = s2 * K_LN2;
    if (lane == 0) {
        ws[(size_t)bu * 64 + 48] = c;
        atomicAdd(out, -gold);
    }
}

__global__ __launch_bounds__(64, 1)
void viterbi_combine_kernel(const float* __restrict__ ws,
                            float* __restrict__ out)
{
    const int b = blockIdx.x, lane = threadIdx.x;
    const float* f = ws + (size_t)(2 * b) * 64;
    const float* g = ws + (size_t)(2 * b + 1) * 64;
    float v = -3.0e38f;
    if (lane < NK) v = f[lane] + g[lane];
    float mm = v;
    #pragma unroll
    for (int o = 32; o; o >>= 1) mm = fmaxf(mm, __shfl_xor(mm, o, 64));
    float e = (lane < NK) ? __expf(v - mm) : 0.f;
    #pragma unroll
    for (int o = 32; o; o >>= 1) e += __shfl_xor(e, o, 64);
    if (lane == 0) atomicAdd(out, __logf(e) + mm + f[NK] + g[NK]);
}

extern "C" void kernel_launch(void* const* d_in, const int* in_sizes, int n_in,
                              void* d_out, int out_size, void* d_ws, size_t ws_size,
                              hipStream_t stream) {
    const float* feats   = (const float*)d_in[0];
    const int*   targets = (const int*)d_in[1];
    const int*   lengths = (const int*)d_in[2];
    float*       out     = (float*)d_out;
    float*       ws      = (float*)d_ws;

    hipMemsetAsync(out, 0, sizeof(float), stream);
    viterbi_chain_kernel<<<dim3(2 * NB), dim3(64), 0, stream>>>(feats, targets, lengths, out, ws);
    viterbi_combine_kernel<<<dim3(NB), dim3(64), 0, stream>>>(ws, out);
}

// Round 7
// 459.098 us; speedup vs baseline: 1.1042x; 1.1042x over previous
//
#include <hip/hip_runtime.h>

// ViterbiLoss (CRF forward) on MI355X — v7: single-wave chains + PINNED register
// prefetch ring. R6 evidence: v6b chain ran 217.8us with VGPR_Count=48 — the
// compiler collapsed the 3x48 prefetch ring (sank loads to uses), exposing full
// memory latency on all 127 serial steps (4100 cy/step, VALUBusy 5.9%).
// v7 delta: __builtin_amdgcn_sched_barrier(0) after each step's load-issue pins
// loads 2-3 steps ahead of use (regalloc must keep them live -> VGPR ~130-190).
// vmcnt encodability (max 63) forces per-direction depth:
//   forward:  depth-2, 48 scalar column loads/buffer (coalesced 192B across
//             lanes); consume waits to 48 outstanding -> vmcnt(48) encodable.
//   backward: depth-3, 12 float4 row loads/buffer; waits to 24 -> vmcnt(24).
// Math (unchanged): meet-in-the-middle. For batch b, last=len-1, m=last/2:
//   forward  chain: s_t[j] = lse_i(M_t[i,j] + s_{t-1}[i]),  t = 1..m
//   backward chain: g_t[i] = lse_j(M_{t+1}[i,j] + g_{t+1}[j]), t = last-2..m,
//                   init g_{last-1}[i] = M_last[i,STOP]
//   result_b = lse_k(s_m[k] + g_m[k]);  total = sum_b result_b - gold.
// ONE WAVE per chain (256 blocks x 64 threads). Lane j owns state j; s[i]
// broadcast via v_readlane (constant index -> SGPR operand). No LDS, no
// barriers in the hot loop. State in log2 domain pinned to lane 0 (no overflow,
// no max reduce); natural-log offset accumulated in c.

#define NB 128
#define NT 256
#define NK 48
#define NKK (NK * NK)          // 2304
#define TAG_START 46
#define TAG_STOP 47
#define K_LOG2E 1.4426950408889634f
#define K_LN2   0.6931471805599453f

#define DECL48(v) \
  float v##0,v##1,v##2,v##3,v##4,v##5,v##6,v##7,v##8,v##9,v##10,v##11, \
        v##12,v##13,v##14,v##15,v##16,v##17,v##18,v##19,v##20,v##21,v##22,v##23, \
        v##24,v##25,v##26,v##27,v##28,v##29,v##30,v##31,v##32,v##33,v##34,v##35, \
        v##36,v##37,v##38,v##39,v##40,v##41,v##42,v##43,v##44,v##45,v##46,v##47;

// forward: lane j owns column j; element i at p[i*NK] (coalesced across lanes)
#define LD48C(v, p) \
  v##0 =(p)[0*NK];  v##1 =(p)[1*NK];  v##2 =(p)[2*NK];  v##3 =(p)[3*NK]; \
  v##4 =(p)[4*NK];  v##5 =(p)[5*NK];  v##6 =(p)[6*NK];  v##7 =(p)[7*NK]; \
  v##8 =(p)[8*NK];  v##9 =(p)[9*NK];  v##10=(p)[10*NK]; v##11=(p)[11*NK]; \
  v##12=(p)[12*NK]; v##13=(p)[13*NK]; v##14=(p)[14*NK]; v##15=(p)[15*NK]; \
  v##16=(p)[16*NK]; v##17=(p)[17*NK]; v##18=(p)[18*NK]; v##19=(p)[19*NK]; \
  v##20=(p)[20*NK]; v##21=(p)[21*NK]; v##22=(p)[22*NK]; v##23=(p)[23*NK]; \
  v##24=(p)[24*NK]; v##25=(p)[25*NK]; v##26=(p)[26*NK]; v##27=(p)[27*NK]; \
  v##28=(p)[28*NK]; v##29=(p)[29*NK]; v##30=(p)[30*NK]; v##31=(p)[31*NK]; \
  v##32=(p)[32*NK]; v##33=(p)[33*NK]; v##34=(p)[34*NK]; v##35=(p)[35*NK]; \
  v##36=(p)[36*NK]; v##37=(p)[37*NK]; v##38=(p)[38*NK]; v##39=(p)[39*NK]; \
  v##40=(p)[40*NK]; v##41=(p)[41*NK]; v##42=(p)[42*NK]; v##43=(p)[43*NK]; \
  v##44=(p)[44*NK]; v##45=(p)[45*NK]; v##46=(p)[46*NK]; v##47=(p)[47*NK];

// backward: lane i owns row i; 48 contiguous floats, 192B-aligned -> 12x float4
#define LD48R(v, p) { \
  const float4* q_ = (const float4*)(p); \
  float4 r0_=q_[0], r1_=q_[1], r2_ =q_[2],  r3_ =q_[3]; \
  float4 r4_=q_[4], r5_=q_[5], r6_ =q_[6],  r7_ =q_[7]; \
  float4 r8_=q_[8], r9_=q_[9], r10_=q_[10], r11_=q_[11]; \
  v##0 =r0_.x;  v##1 =r0_.y;  v##2 =r0_.z;  v##3 =r0_.w; \
  v##4 =r1_.x;  v##5 =r1_.y;  v##6 =r1_.z;  v##7 =r1_.w; \
  v##8 =r2_.x;  v##9 =r2_.y;  v##10=r2_.z;  v##11=r2_.w; \
  v##12=r3_.x;  v##13=r3_.y;  v##14=r3_.z;  v##15=r3_.w; \
  v##16=r4_.x;  v##17=r4_.y;  v##18=r4_.z;  v##19=r4_.w; \
  v##20=r5_.x;  v##21=r5_.y;  v##22=r5_.z;  v##23=r5_.w; \
  v##24=r6_.x;  v##25=r6_.y;  v##26=r6_.z;  v##27=r6_.w; \
  v##28=r7_.x;  v##29=r7_.y;  v##30=r7_.z;  v##31=r7_.w; \
  v##32=r8_.x;  v##33=r8_.y;  v##34=r8_.z;  v##35=r8_.w; \
  v##36=r9_.x;  v##37=r9_.y;  v##38=r9_.z;  v##39=r9_.w; \
  v##40=r10_.x; v##41=r10_.y; v##42=r10_.z; v##43=r10_.w; \
  v##44=r11_.x; v##45=r11_.y; v##46=r11_.z; v##47=r11_.w; }

// broadcast of lane i's s2 (uniform across wave -> SGPR), constant lane index
#define RL(i) __int_as_float(__builtin_amdgcn_readlane(__float_as_int(s2), (i)))
// one LSE term: exp2(M*log2e + s2_i) = e^{M + s_i}
#define TT(v,i) exp2f(__builtin_fmaf(v##i, K_LOG2E, RL(i)))

#define SUMTREE48(v) \
 ((((((TT(v,0)+TT(v,1))+(TT(v,2)+TT(v,3)))+((TT(v,4)+TT(v,5))+(TT(v,6)+TT(v,7)))) + \
    (((TT(v,8)+TT(v,9))+(TT(v,10)+TT(v,11)))+((TT(v,12)+TT(v,13))+(TT(v,14)+TT(v,15))))) + \
   ((((TT(v,16)+TT(v,17))+(TT(v,18)+TT(v,19)))+((TT(v,20)+TT(v,21))+(TT(v,22)+TT(v,23)))) + \
    (((TT(v,24)+TT(v,25))+(TT(v,26)+TT(v,27)))+((TT(v,28)+TT(v,29))+(TT(v,30)+TT(v,31)))))) + \
  ((((TT(v,32)+TT(v,33))+(TT(v,34)+TT(v,35)))+((TT(v,36)+TT(v,37))+(TT(v,38)+TT(v,39)))) + \
   (((TT(v,40)+TT(v,41))+(TT(v,42)+TT(v,43)))+((TT(v,44)+TT(v,45))+(TT(v,46)+TT(v,47))))))

// One chain step: consume buffer v (holds matrix u), refill it for u+D, pin
// the loads with sched_barrier(0) so they cannot sink toward their use.
#define STEP48(v, LDM, D) { \
  float acc_ = SUMTREE48(v); \
  { int up_ = u + (D); if (up_ > nsteps) up_ = nsteps; \
    const float* p_ = basep + (long)up_ * dstep; LDM(v, p_) } \
  __builtin_amdgcn_sched_barrier(0); \
  float l2_ = __log2f(acc_); \
  float d2_ = __int_as_float(__builtin_amdgcn_readfirstlane(__float_as_int(l2_))); \
  s2 = l2_ - d2_; \
  c  = __builtin_fmaf(d2_, K_LN2, c); \
}

// depth-2 ring (forward: 48 scalar loads/buffer -> keep outstanding <= 96,
// consume-wait = 48 outstanding, vmcnt-encodable)
#define CHAIN2(LDM) { \
  DECL48(A) DECL48(B) \
  { const float* p_ = basep + dstep; LDM(A, p_) } \
  { int up_ = (2 > nsteps) ? nsteps : 2; \
    const float* p_ = basep + (long)up_ * dstep; LDM(B, p_) } \
  int u = 1; \
  for (;;) { \
    STEP48(A, LDM, 2) if (++u > nsteps) break; \
    STEP48(B, LDM, 2) if (++u > nsteps) break; \
  } \
}

// depth-3 ring (backward: 12 float4 loads/buffer -> consume-wait = 24)
#define CHAIN3(LDM) { \
  DECL48(A) DECL48(B) DECL48(C) \
  { const float* p_ = basep + dstep; LDM(A, p_) } \
  { int up_ = (2 > nsteps) ? nsteps : 2; \
    const float* p_ = basep + (long)up_ * dstep; LDM(B, p_) } \
  { int up_ = (3 > nsteps) ? nsteps : 3; \
    const float* p_ = basep + (long)up_ * dstep; LDM(C, p_) } \
  int u = 1; \
  for (;;) { \
    STEP48(A, LDM, 3) if (++u > nsteps) break; \
    STEP48(B, LDM, 3) if (++u > nsteps) break; \
    STEP48(C, LDM, 3) if (++u > nsteps) break; \
  } \
}

__global__ __launch_bounds__(64, 1)
void viterbi_chain_kernel(const float* __restrict__ feats,
                          const int* __restrict__ targets,
                          const int* __restrict__ lengths,
                          float* __restrict__ out,
                          float* __restrict__ ws)
{
    const int bu   = blockIdx.x;
    const int b    = bu >> 1;
    const int dir  = bu & 1;
    const int lane = threadIdx.x;
    const int len = lengths[b], last = len - 1, m = last >> 1;
    const float* __restrict__ fb = feats + (size_t)b * (NT * NKK);

    // ---- gold slice: fwd owns t in [0,m], bwd owns t in [m+1,last] ----
    float gold = 0.f;
    {
        int t   = dir ? (m + 1 + lane) : lane;
        int tmx = dir ? last : m;
        while (t <= tmx) { gold += fb[(size_t)t * NKK + targets[b * NT + t]]; t += 64; }
        #pragma unroll
        for (int o = 32; o; o >>= 1) gold += __shfl_down(gold, o, 64);
    }

    const int ooc = (lane < NK) ? lane : (NK - 1);   // lanes 48..63 duplicate state 47
    int nsteps = dir ? (last - 1 - m) : m;
    if (nsteps < 0) nsteps = 0;

    // ---- init state (log2 domain): s2 = s_natural * log2e ----
    float s2, c = 0.f;
    if (dir) s2 = (last == 0) ? ((ooc == TAG_STOP) ? 0.f : -1e30f)
                              : fb[(size_t)last * NKK + (size_t)ooc * NK + TAG_STOP] * K_LOG2E;
    else     s2 = fb[TAG_START * NK + ooc] * K_LOG2E;

    if (nsteps > 0) {
        if (dir) {  // backward: lane i reads row i (contiguous 192B, float4 x12)
            const float* basep = fb + (size_t)last * NKK + (size_t)ooc * NK;
            const long dstep = -(long)NKK;
            CHAIN3(LD48R)
        } else {    // forward: lane j reads column j; each load inst is a
                    // contiguous 192B row across lanes (coalesced)
            const float* basep = fb + ooc;
            const long dstep = (long)NKK;
            CHAIN2(LD48C)
        }
    }

    // ---- emit: 48 natural-log values + natural-log offset at [48] ----
    if (lane < NK) ws[(size_t)bu * 64 + lane] = s2 * K_LN2;
    if (lane == 0) {
        ws[(size_t)bu * 64 + 48] = c;
        atomicAdd(out, -gold);
    }
}

__global__ __launch_bounds__(64, 1)
void viterbi_combine_kernel(const float* __restrict__ ws,
                            float* __restrict__ out)
{
    const int b = blockIdx.x, lane = threadIdx.x;
    const float* f = ws + (size_t)(2 * b) * 64;
    const float* g = ws + (size_t)(2 * b + 1) * 64;
    float v = -3.0e38f;
    if (lane < NK) v = f[lane] + g[lane];
    float mm = v;
    #pragma unroll
    for (int o = 32; o; o >>= 1) mm = fmaxf(mm, __shfl_xor(mm, o, 64));
    float e = (lane < NK) ? __expf(v - mm) : 0.f;
    #pragma unroll
    for (int o = 32; o; o >>= 1) e += __shfl_xor(e, o, 64);
    if (lane == 0) atomicAdd(out, __logf(e) + mm + f[NK] + g[NK]);
}

extern "C" void kernel_launch(void* const* d_in, const int* in_sizes, int n_in,
                              void* d_out, int out_size, void* d_ws, size_t ws_size,
                              hipStream_t stream) {
    const float* feats   = (const float*)d_in[0];
    const int*   targets = (const int*)d_in[1];
    const int*   lengths = (const int*)d_in[2];
    float*       out     = (float*)d_out;
    float*       ws      = (float*)d_ws;

    hipMemsetAsync(out, 0, sizeof(float), stream);
    viterbi_chain_kernel<<<dim3(2 * NB), dim3(64), 0, stream>>>(feats, targets, lengths, out, ws);
    viterbi_combine_kernel<<<dim3(NB), dim3(64), 0, stream>>>(ws, out);
}

// Round 13
// 426.507 us; speedup vs baseline: 1.1886x; 1.0764x over previous
//
#include <hip/hip_runtime.h>

// ViterbiLoss (CRF forward) on MI355X — v8 (6th submit; broker timeouts x5 on
// this version; six audit passes, zero findings: ring rotation, vmcnt
// encodability, DS in-order write->read, WAR on ds_write sources, bank
// aliasing, IR motion across sched_barrier, len=1/nsteps<3 edges, gold
// reduction, launch_bounds/LDS/ws budgets).
// Meet-in-the-middle (unchanged math): for batch b, last=len-1, m=last/2:
//   forward  chain: s_t[j] = lse_i(M_t[i,j] + s_{t-1}[i]),  t = 1..m
//   backward chain: g_t[i] = lse_j(M_{t+1}[i,j] + g_{t+1}[j]), t = last-2..m,
//                   init g_{last-1}[i] = M_last[i,STOP]
//   result_b = lse_k(s_m[k] + g_m[k]);  total = sum_b result_b - gold.
// ONE WAVE per chain (256 blocks x 64 threads); state in log2 domain pinned to
// lane 0 via readfirstlane (no overflow, no max-reduce); ln-offset in c.
// R6/R7 evidence: forward's 48 scalar column loads/buffer exceed vmcnt
// encodability (max 63) -> compiler over-drains, prefetch collapses, ~3400
// cy/step memory wait. v8: forward loads ROWS as 9x float4/lane (coalesced
// 1KB/inst), 3-deep REGISTER ring (27 loads in flight, waits at vmcnt(18)),
// transpose via 2-buffer LDS ping-pong — no barrier needed (single wave,
// in-order DS pipe), phases pinned with sched_barrier(0). Compute reads the
// column straight from LDS (48 ds_read_b32, <=2-way bank alias = free).
// Backward keeps v7's pinned depth-3 float4 register ring.

#define NB 128
#define NT 256
#define NK 48
#define NKK (NK * NK)          // 2304
#define TAG_START 46
#define TAG_STOP 47
#define K_LOG2E 1.4426950408889634f
#define K_LN2   0.6931471805599453f

#if __has_builtin(__builtin_amdgcn_exp2f)
#define EXP2(x) __builtin_amdgcn_exp2f(x)
#else
#define EXP2(x) exp2f(x)
#endif

#define SB() __builtin_amdgcn_sched_barrier(0)

// broadcast of lane i's s2 (uniform across wave -> SGPR), constant lane index
#define RL(i) __int_as_float(__builtin_amdgcn_readlane(__float_as_int(s2), (i)))

// ===================== backward (row-ownership, v7 path) =====================
#define DECL48(v) \
  float v##0,v##1,v##2,v##3,v##4,v##5,v##6,v##7,v##8,v##9,v##10,v##11, \
        v##12,v##13,v##14,v##15,v##16,v##17,v##18,v##19,v##20,v##21,v##22,v##23, \
        v##24,v##25,v##26,v##27,v##28,v##29,v##30,v##31,v##32,v##33,v##34,v##35, \
        v##36,v##37,v##38,v##39,v##40,v##41,v##42,v##43,v##44,v##45,v##46,v##47;

#define LD48R(v, p) { \
  const float4* q_ = (const float4*)(p); \
  float4 r0_=q_[0], r1_=q_[1], r2_ =q_[2],  r3_ =q_[3]; \
  float4 r4_=q_[4], r5_=q_[5], r6_ =q_[6],  r7_ =q_[7]; \
  float4 r8_=q_[8], r9_=q_[9], r10_=q_[10], r11_=q_[11]; \
  v##0 =r0_.x;  v##1 =r0_.y;  v##2 =r0_.z;  v##3 =r0_.w; \
  v##4 =r1_.x;  v##5 =r1_.y;  v##6 =r1_.z;  v##7 =r1_.w; \
  v##8 =r2_.x;  v##9 =r2_.y;  v##10=r2_.z;  v##11=r2_.w; \
  v##12=r3_.x;  v##13=r3_.y;  v##14=r3_.z;  v##15=r3_.w; \
  v##16=r4_.x;  v##17=r4_.y;  v##18=r4_.z;  v##19=r4_.w; \
  v##20=r5_.x;  v##21=r5_.y;  v##22=r5_.z;  v##23=r5_.w; \
  v##24=r6_.x;  v##25=r6_.y;  v##26=r6_.z;  v##27=r6_.w; \
  v##28=r7_.x;  v##29=r7_.y;  v##30=r7_.z;  v##31=r7_.w; \
  v##32=r8_.x;  v##33=r8_.y;  v##34=r8_.z;  v##35=r8_.w; \
  v##36=r9_.x;  v##37=r9_.y;  v##38=r9_.z;  v##39=r9_.w; \
  v##40=r10_.x; v##41=r10_.y; v##42=r10_.z; v##43=r10_.w; \
  v##44=r11_.x; v##45=r11_.y; v##46=r11_.z; v##47=r11_.w; }

#define TT(v,i) EXP2(__builtin_fmaf(v##i, vlog2e, RL(i)))

#define SUMTREE48(v) \
 ((((((TT(v,0)+TT(v,1))+(TT(v,2)+TT(v,3)))+((TT(v,4)+TT(v,5))+(TT(v,6)+TT(v,7)))) + \
    (((TT(v,8)+TT(v,9))+(TT(v,10)+TT(v,11)))+((TT(v,12)+TT(v,13))+(TT(v,14)+TT(v,15))))) + \
   ((((TT(v,16)+TT(v,17))+(TT(v,18)+TT(v,19)))+((TT(v,20)+TT(v,21))+(TT(v,22)+TT(v,23)))) + \
    (((TT(v,24)+TT(v,25))+(TT(v,26)+TT(v,27)))+((TT(v,28)+TT(v,29))+(TT(v,30)+TT(v,31)))))) + \
  ((((TT(v,32)+TT(v,33))+(TT(v,34)+TT(v,35)))+((TT(v,36)+TT(v,37))+(TT(v,38)+TT(v,39)))) + \
   (((TT(v,40)+TT(v,41))+(TT(v,42)+TT(v,43)))+((TT(v,44)+TT(v,45))+(TT(v,46)+TT(v,47))))))

#define STEPB(v) { \
  float acc_ = SUMTREE48(v); \
  { int up_ = u + 3; if (up_ > nsteps) up_ = nsteps; \
    const float* p_ = basep + (long)up_ * dstep; LD48R(v, p_) } \
  SB(); \
  float l2_ = __log2f(acc_); \
  float d2_ = __int_as_float(__builtin_amdgcn_readfirstlane(__float_as_int(l2_))); \
  s2 = l2_ - d2_; \
  c  = __builtin_fmaf(d2_, K_LN2, c); \
}

#define CHAINB() { \
  DECL48(A) DECL48(B) DECL48(C) \
  { const float* p_ = basep + dstep; LD48R(A, p_) } \
  { int up_ = (2 > nsteps) ? nsteps : 2; \
    const float* p_ = basep + (long)up_ * dstep; LD48R(B, p_) } \
  { int up_ = (3 > nsteps) ? nsteps : 3; \
    const float* p_ = basep + (long)up_ * dstep; LD48R(C, p_) } \
  int u = 1; \
  for (;;) { \
    STEPB(A) if (++u > nsteps) break; \
    STEPB(B) if (++u > nsteps) break; \
    STEPB(C) if (++u > nsteps) break; \
  } \
}

// ================= forward (row loads + single-wave LDS transpose) ===========
#define DECL9(R) float4 R##0,R##1,R##2,R##3,R##4,R##5,R##6,R##7,R##8;

#define GLD9(R, base) { const float4* q_ = (const float4*)(base); \
  R##0=q_[lane];     R##1=q_[lane+64];  R##2=q_[lane+128]; \
  R##3=q_[lane+192]; R##4=q_[lane+256]; R##5=q_[lane+320]; \
  R##6=q_[lane+384]; R##7=q_[lane+448]; R##8=q_[lane+512]; }

#define WRT9(R, tb) { float4* w_ = (float4*)(tb); \
  w_[lane]=R##0;     w_[lane+64]=R##1;  w_[lane+128]=R##2; \
  w_[lane+192]=R##3; w_[lane+256]=R##4; w_[lane+320]=R##5; \
  w_[lane+384]=R##6; w_[lane+448]=R##7; w_[lane+512]=R##8; }

#define FT(TBR,k) EXP2(__builtin_fmaf(TBF[TBR][k][jc], vlog2e, RL(k)))

#define FSUM(TBR) \
 ((((((FT(TBR,0)+FT(TBR,1))+(FT(TBR,2)+FT(TBR,3)))+((FT(TBR,4)+FT(TBR,5))+(FT(TBR,6)+FT(TBR,7)))) + \
    (((FT(TBR,8)+FT(TBR,9))+(FT(TBR,10)+FT(TBR,11)))+((FT(TBR,12)+FT(TBR,13))+(FT(TBR,14)+FT(TBR,15))))) + \
   ((((FT(TBR,16)+FT(TBR,17))+(FT(TBR,18)+FT(TBR,19)))+((FT(TBR,20)+FT(TBR,21))+(FT(TBR,22)+FT(TBR,23)))) + \
    (((FT(TBR,24)+FT(TBR,25))+(FT(TBR,26)+FT(TBR,27)))+((FT(TBR,28)+FT(TBR,29))+(FT(TBR,30)+FT(TBR,31)))))) + \
  ((((FT(TBR,32)+FT(TBR,33))+(FT(TBR,34)+FT(TBR,35)))+((FT(TBR,36)+FT(TBR,37))+(FT(TBR,38)+FT(TBR,39)))) + \
   (((FT(TBR,40)+FT(TBR,41))+(FT(TBR,42)+FT(TBR,43)))+((FT(TBR,44)+FT(TBR,45))+(FT(TBR,46)+FT(TBR,47))))))

// iter u: issue glob(u+3)->Ri; compute from TBF[TBR]=M_u; write Rw=glob(u+1)
// into TBF[TBW] (compiler inserts counted vmcnt(18) before the writes).
#define STEPF(Ri, Rw, TBR, TBW) { \
  { int up_ = u + 3; if (up_ > nsteps) up_ = nsteps; \
    GLD9(Ri, fb + (size_t)up_ * NKK) } \
  SB(); \
  float acc_ = FSUM(TBR); \
  SB(); \
  WRT9(Rw, TBF[TBW]) \
  SB(); \
  float l2_ = __log2f(acc_); \
  float d2_ = __int_as_float(__builtin_amdgcn_readfirstlane(__float_as_int(l2_))); \
  s2 = l2_ - d2_; \
  c  = __builtin_fmaf(d2_, K_LN2, c); \
}

__global__ __launch_bounds__(64, 1)
void viterbi_chain_kernel(const float* __restrict__ feats,
                          const int* __restrict__ targets,
                          const int* __restrict__ lengths,
                          float* __restrict__ out,
                          float* __restrict__ ws)
{
    const int bu   = blockIdx.x;
    const int b    = bu >> 1;
    const int dir  = bu & 1;
    const int lane = threadIdx.x;
    const int len = lengths[b], last = len - 1, m = last >> 1;
    const float* __restrict__ fb = feats + (size_t)b * (NT * NKK);
    const float vlog2e = K_LOG2E;

    __shared__ __align__(16) float TBF[2][NK][NK];   // 18 KB, fwd transpose buf

    // ---- gold slice: fwd owns t in [0,m], bwd owns t in [m+1,last] ----
    float gold = 0.f;
    {
        int t   = dir ? (m + 1 + lane) : lane;
        int tmx = dir ? last : m;
        while (t <= tmx) { gold += fb[(size_t)t * NKK + targets[b * NT + t]]; t += 64; }
        #pragma unroll
        for (int o = 32; o; o >>= 1) gold += __shfl_down(gold, o, 64);
    }

    const int ooc = (lane < NK) ? lane : (NK - 1);   // backward row / state id
    const int jc  = ooc;                             // forward column id
    int nsteps = dir ? (last - 1 - m) : m;
    if (nsteps < 0) nsteps = 0;

    // ---- init state (log2 domain): s2 = s_natural * log2e ----
    float s2, c = 0.f;
    if (dir) s2 = (last == 0) ? ((ooc == TAG_STOP) ? 0.f : -1e30f)
                              : fb[(size_t)last * NKK + (size_t)ooc * NK + TAG_STOP] * K_LOG2E;
    else     s2 = fb[TAG_START * NK + ooc] * K_LOG2E;

    if (nsteps > 0) {
        if (dir) {  // backward: lane i owns row i; contiguous float4 x12 loads
            const float* basep = fb + (size_t)last * NKK + (size_t)ooc * NK;
            const long dstep = -(long)NKK;
            CHAINB()
        } else {    // forward: row-chunk loads + LDS transpose, column compute
            DECL9(R0f) DECL9(R1f) DECL9(R2f)
            { int u_ = (1 > nsteps) ? nsteps : 1; GLD9(R1f, fb + (size_t)u_ * NKK) }
            { int u_ = (2 > nsteps) ? nsteps : 2; GLD9(R2f, fb + (size_t)u_ * NKK) }
            { int u_ = (3 > nsteps) ? nsteps : 3; GLD9(R0f, fb + (size_t)u_ * NKK) }
            WRT9(R1f, TBF[1])                        // M_1 -> TBF[1]
            int u = 1;
            for (;;) {                               // glob(k) lives in R{k%3}
                STEPF(R1f, R2f, 1, 0) if (++u > nsteps) break;  // u%6==1
                STEPF(R2f, R0f, 0, 1) if (++u > nsteps) break;  // u%6==2
                STEPF(R0f, R1f, 1, 0) if (++u > nsteps) break;  // u%6==3
                STEPF(R1f, R2f, 0, 1) if (++u > nsteps) break;  // u%6==4
                STEPF(R2f, R0f, 1, 0) if (++u > nsteps) break;  // u%6==5
                STEPF(R0f, R1f, 0, 1) if (++u > nsteps) break;  // u%6==0
            }
        }
    }

    // ---- emit: 48 natural-log values + natural-log offset at [48] ----
    if (lane < NK) ws[(size_t)bu * 64 + lane] = s2 * K_LN2;
    if (lane == 0) {
        ws[(size_t)bu * 64 + 48] = c;
        atomicAdd(out, -gold);
    }
}

__global__ __launch_bounds__(64, 1)
void viterbi_combine_kernel(const float* __restrict__ ws,
                            float* __restrict__ out)
{
    const int b = blockIdx.x, lane = threadIdx.x;
    const float* f = ws + (size_t)(2 * b) * 64;
    const float* g = ws + (size_t)(2 * b + 1) * 64;
    float v = -3.0e38f;
    if (lane < NK) v = f[lane] + g[lane];
    float mm = v;
    #pragma unroll
    for (int o = 32; o; o >>= 1) mm = fmaxf(mm, __shfl_xor(mm, o, 64));
    float e = (lane < NK) ? __expf(v - mm) : 0.f;
    #pragma unroll
    for (int o = 32; o; o >>= 1) e += __shfl_xor(e, o, 64);
    if (lane == 0) atomicAdd(out, __logf(e) + mm + f[NK] + g[NK]);
}

extern "C" void kernel_launch(void* const* d_in, const int* in_sizes, int n_in,
                              void* d_out, int out_size, void* d_ws, size_t ws_size,
                              hipStream_t stream) {
    const float* feats   = (const float*)d_in[0];
    const int*   targets = (const int*)d_in[1];
    const int*   lengths = (const int*)d_in[2];
    float*       out     = (float*)d_out;
    float*       ws      = (float*)d_ws;

    hipMemsetAsync(out, 0, sizeof(float), stream);
    viterbi_chain_kernel<<<dim3(2 * NB), dim3(64), 0, stream>>>(feats, targets, lengths, out, ws);
    viterbi_combine_kernel<<<dim3(NB), dim3(64), 0, stream>>>(ws, out);
}